// Round 3
// baseline (119.003 us; speedup 1.0000x reference)
//
#include <hip/hip_runtime.h>

// BSplineKAN: out[b,c] = sum_i cp[c,i] * N_{i,3}(clip(x[b,c], -0.99, 0.99))
// Uniform unclamped knots on [-1,1] (h = 2/11) -> every in-range basis is a
// translate of the cardinal cubic B-spline; OOR indices are dropped (matches
// the reference's truncated Cox-de Boor). Fold cp into per-(channel,interval)
// cubic coefficients P_{c,j}(u) = a0 + u(a1 + u(a2 + u*a3)), u=(x-t_j)/h.
//
// R1: AoS float4 LDS table had ~8-way bank-group conflicts on the gather
// (lane channel strides by 4 -> (c*44+j*16)/4 mod 32 clusters in 8 groups).
// R2/R3: SoA (4 scalar arrays, odd stride 11) -> bank = (12*lane+11e+j) % 32,
// j-window spreads across the stride-4 gaps => near-conflict-free b32 reads,
// one shared vaddr + immediate offsets. Nontemporal global access (pure
// streaming, no reuse) + 2x unroll for memory-level parallelism.
// R3 fix: __builtin_nontemporal_* needs clang ext-vector types, not
// HIP_vector_type structs.

typedef float fvec4 __attribute__((ext_vector_type(4)));

constexpr int CH  = 64;      // channels
constexpr int PCP = 8;       // control points per channel
constexpr int NJ  = 11;      // intervals
constexpr int TBL = CH * NJ; // 704 floats per coefficient array

__device__ __forceinline__ float eval_elem(float v, int row,
                                           const float* __restrict__ c0,
                                           const float* __restrict__ c1,
                                           const float* __restrict__ c2,
                                           const float* __restrict__ c3) {
    float xx = fminf(fmaxf(v, -0.99f), 0.99f);
    float fz = fmaf(xx, 5.5f, 5.5f);   // (x+1)*5.5 in [0.055, 10.945]
    int   j  = (int)fz;                // trunc; always in [0,10]
    float u  = fz - (float)j;
    int   o  = row + j;
    return fmaf(fmaf(fmaf(c3[o], u, c2[o]), u, c1[o]), u, c0[o]);
}

__global__ __launch_bounds__(256) void bspline_kan_kernel(
    const float* __restrict__ x,
    const float* __restrict__ cp,
    float* __restrict__ out,
    int n4)
{
    __shared__ float c0[TBL], c1[TBL], c2[TBL], c3[TBL];

    // Build per-(channel, interval) cubic coefficients (SoA).
    for (int t = threadIdx.x; t < TBL; t += 256) {
        int c = t / NJ;
        int j = t - c * NJ;
        float p[4];
#pragma unroll
        for (int r = 0; r < 4; ++r) {
            int i = j - 3 + r;
            p[r] = (i >= 0 && i < PCP) ? cp[c * PCP + i] : 0.0f;
        }
        c0[t] = (p[0] + 4.0f * p[1] + p[2]) * (1.0f / 6.0f);
        c1[t] = (p[2] - p[0]) * 0.5f;
        c2[t] = (p[0] - 2.0f * p[1] + p[2]) * 0.5f;
        c3[t] = (p[3] - p[0] + 3.0f * (p[1] - p[2])) * (1.0f / 6.0f);
    }
    __syncthreads();

    const fvec4* __restrict__ x4 = (const fvec4*)x;
    fvec4* __restrict__ o4 = (fvec4*)out;

    int idx    = blockIdx.x * 256 + threadIdx.x;
    int stride = gridDim.x * 256;

    // 4 consecutive elements = 4 consecutive channels; stride*4 % 64 == 0, so
    // the channel rows are loop-invariant (and shared by the unrolled pair).
    int base_c = (idx << 2) & (CH - 1);
    int row0 = base_c * NJ;
    int row1 = row0 + NJ;
    int row2 = row0 + 2 * NJ;
    int row3 = row0 + 3 * NJ;

    for (int i = idx; i < n4; i += 2 * stride) {
        int i2 = i + stride;
        bool has2 = (i2 < n4);
        fvec4 xa = __builtin_nontemporal_load(&x4[i]);
        fvec4 xb = has2 ? __builtin_nontemporal_load(&x4[i2]) : xa;

        fvec4 ra, rb;
        ra.x = eval_elem(xa.x, row0, c0, c1, c2, c3);
        ra.y = eval_elem(xa.y, row1, c0, c1, c2, c3);
        ra.z = eval_elem(xa.z, row2, c0, c1, c2, c3);
        ra.w = eval_elem(xa.w, row3, c0, c1, c2, c3);
        rb.x = eval_elem(xb.x, row0, c0, c1, c2, c3);
        rb.y = eval_elem(xb.y, row1, c0, c1, c2, c3);
        rb.z = eval_elem(xb.z, row2, c0, c1, c2, c3);
        rb.w = eval_elem(xb.w, row3, c0, c1, c2, c3);

        __builtin_nontemporal_store(ra, &o4[i]);
        if (has2) __builtin_nontemporal_store(rb, &o4[i2]);
    }
}

extern "C" void kernel_launch(void* const* d_in, const int* in_sizes, int n_in,
                              void* d_out, int out_size, void* d_ws, size_t ws_size,
                              hipStream_t stream) {
    const float* x  = (const float*)d_in[0];   // [262144, 64] fp32
    const float* cp = (const float*)d_in[1];   // [64, 8] fp32
    float* out = (float*)d_out;                // [262144, 64] fp32

    int n4 = in_sizes[0] / 4;                  // 4194304 float4s
    // 2048 blocks = 8 blocks/CU (LDS 11.3 KB -> not limiting); exactly 8
    // float4 iters/thread = 4 unrolled-by-2 iters.
    bspline_kan_kernel<<<2048, 256, 0, stream>>>(x, cp, out, n4);
}

// Round 4
// 115.193 us; speedup vs baseline: 1.0331x; 1.0331x over previous
//
#include <hip/hip_runtime.h>

// BSplineKAN: out[b,c] = sum_i cp[c,i] * N_{i,3}(clip(x[b,c], -0.99, 0.99))
// Uniform unclamped knots on [-1,1] (h = 2/11) -> every in-range basis is a
// translate of the cardinal cubic B-spline; OOR indices are dropped (matches
// the reference's truncated Cox-de Boor). Fold cp into per-(channel,interval)
// cubic coefficients P_{c,j}(u) = a0 + u(a1 + u(a2 + u*a3)), u=(x-t_j)/h.
//
// R1: AoS float4 LDS table -> ~8-way bank-group conflicts on the gather.
// R2/R4: SoA (4 scalar arrays, odd stride 11) -> bank = (12*lane+11e+j)%32,
// near-conflict-free b32 reads, shared vaddr + immediate offsets.
// R4: reverted R3's nontemporal hints — harness restores x via d2d copy just
// before the kernel, so x may be L3-resident (67 MB << 256 MiB Infinity
// Cache); nt loads bypass L3 and force the HBM path. Plain vector access.

typedef float fvec4 __attribute__((ext_vector_type(4)));

constexpr int CH  = 64;      // channels
constexpr int PCP = 8;       // control points per channel
constexpr int NJ  = 11;      // intervals
constexpr int TBL = CH * NJ; // 704 floats per coefficient array

__device__ __forceinline__ float eval_elem(float v, int row,
                                           const float* __restrict__ c0,
                                           const float* __restrict__ c1,
                                           const float* __restrict__ c2,
                                           const float* __restrict__ c3) {
    float xx = fminf(fmaxf(v, -0.99f), 0.99f);
    float fz = fmaf(xx, 5.5f, 5.5f);   // (x+1)*5.5 in [0.055, 10.945]
    int   j  = (int)fz;                // trunc; always in [0,10]
    float u  = fz - (float)j;
    int   o  = row + j;
    return fmaf(fmaf(fmaf(c3[o], u, c2[o]), u, c1[o]), u, c0[o]);
}

__global__ __launch_bounds__(256) void bspline_kan_kernel(
    const float* __restrict__ x,
    const float* __restrict__ cp,
    float* __restrict__ out,
    int n4)
{
    __shared__ float c0[TBL], c1[TBL], c2[TBL], c3[TBL];

    // Build per-(channel, interval) cubic coefficients (SoA).
    for (int t = threadIdx.x; t < TBL; t += 256) {
        int c = t / NJ;
        int j = t - c * NJ;
        float p[4];
#pragma unroll
        for (int r = 0; r < 4; ++r) {
            int i = j - 3 + r;
            p[r] = (i >= 0 && i < PCP) ? cp[c * PCP + i] : 0.0f;
        }
        c0[t] = (p[0] + 4.0f * p[1] + p[2]) * (1.0f / 6.0f);
        c1[t] = (p[2] - p[0]) * 0.5f;
        c2[t] = (p[0] - 2.0f * p[1] + p[2]) * 0.5f;
        c3[t] = (p[3] - p[0] + 3.0f * (p[1] - p[2])) * (1.0f / 6.0f);
    }
    __syncthreads();

    const fvec4* __restrict__ x4 = (const fvec4*)x;
    fvec4* __restrict__ o4 = (fvec4*)out;

    int idx    = blockIdx.x * 256 + threadIdx.x;
    int stride = gridDim.x * 256;

    // 4 consecutive elements = 4 consecutive channels; stride*4 % 64 == 0, so
    // the channel rows are loop-invariant (and shared by the unrolled pair).
    int base_c = (idx << 2) & (CH - 1);
    int row0 = base_c * NJ;
    int row1 = row0 + NJ;
    int row2 = row0 + 2 * NJ;
    int row3 = row0 + 3 * NJ;

    for (int i = idx; i < n4; i += 2 * stride) {
        int i2 = i + stride;
        bool has2 = (i2 < n4);
        fvec4 xa = x4[i];
        fvec4 xb = has2 ? x4[i2] : xa;

        fvec4 ra, rb;
        ra.x = eval_elem(xa.x, row0, c0, c1, c2, c3);
        ra.y = eval_elem(xa.y, row1, c0, c1, c2, c3);
        ra.z = eval_elem(xa.z, row2, c0, c1, c2, c3);
        ra.w = eval_elem(xa.w, row3, c0, c1, c2, c3);
        rb.x = eval_elem(xb.x, row0, c0, c1, c2, c3);
        rb.y = eval_elem(xb.y, row1, c0, c1, c2, c3);
        rb.z = eval_elem(xb.z, row2, c0, c1, c2, c3);
        rb.w = eval_elem(xb.w, row3, c0, c1, c2, c3);

        o4[i] = ra;
        if (has2) o4[i2] = rb;
    }
}

extern "C" void kernel_launch(void* const* d_in, const int* in_sizes, int n_in,
                              void* d_out, int out_size, void* d_ws, size_t ws_size,
                              hipStream_t stream) {
    const float* x  = (const float*)d_in[0];   // [262144, 64] fp32
    const float* cp = (const float*)d_in[1];   // [64, 8] fp32
    float* out = (float*)d_out;                // [262144, 64] fp32

    int n4 = in_sizes[0] / 4;                  // 4194304 float4s
    // 2048 blocks = 8 blocks/CU (LDS 11.3 KB -> not limiting); exactly 8
    // float4 iters/thread = 4 unrolled-by-2 iters.
    bspline_kan_kernel<<<2048, 256, 0, stream>>>(x, cp, out, n4);
}